// Round 31
// baseline (251.145 us; speedup 1.0000x reference)
//
#include <hip/hip_runtime.h>
#include <math.h>

#define NB 64
#define NT 2048
#define NF 40
#define HO 2046
#define WO 38
#define HW 77748          // HO*WO
#define GIN 304
#define NG 96
#define GH 32

// d_out float offsets (flat concat in return order)
#define OFF_LOGITS 0
#define OFF_SUM    128
#define OFF_MUL    2176
#define OFF_SM     4192384
#define OFF_L2     8382592
#define OFF_GRU    12572800
#define OFF_DCN    16763008
#define OFF_DCNW   56569984
#define OFF_DCNB   56570056
// scratch aliases inside d_out:
#define OFF_GI     OFF_MUL    // bf16 gi tensor (12,570,624 ushorts = 6.29M floats) fits here
#define OFF_WIHR   OFF_GRU    // bf16 w layouts (2 x 15,744 floats), consumed by K2, overwritten by K3

#define CG_SCALE (-1.44269504088896340736f)
#define CN_SCALE ( 2.88539008177792681472f)

// ws layout (floats) for the big-ws path: [0, XSF) bf16 xs tensor
// (64*2046*304 ushorts), then softmax partials.
#define XSF 19903488

typedef float f32x2 __attribute__((ext_vector_type(2)));
typedef float f32x4 __attribute__((ext_vector_type(4)));
typedef short bf16x8 __attribute__((ext_vector_type(8)));
typedef unsigned long long u64;

__device__ __forceinline__ float rcp_f(float x){
  return __builtin_amdgcn_rcpf(x);
}
__device__ __forceinline__ float tanh_f(float x){
  return 1.0f - 2.0f * rcp_f(__expf(2.0f * x) + 1.0f);
}
__device__ __forceinline__ unsigned bf16r(float x){   // RNE f32->bf16
  unsigned u = __float_as_uint(x);
  return (u + 0x7FFFu + ((u >> 16) & 1u)) >> 16;
}
__device__ __forceinline__ float bf2f(unsigned short v){
  return __uint_as_float(((unsigned)v) << 16);
}

#define WKP 328

// ---------------- K1 (templated on XSW): fused offset-conv + deformable
// bilinear + DCN einsum + merged k0 slice (writes both bf16 w layouts +
// dcn_w/dcn_b passthrough). XSW=1: also emit bf16 xs rows into ws (r30).
#define XLR 26
template<int XSW>
__global__ __launch_bounds__(256, 6) void k1_deform_t(
    const float* __restrict__ x, const float* __restrict__ offset_w,
    const float* __restrict__ offset_b, const float* __restrict__ dcn_w,
    const float* __restrict__ dcn_b, const float* __restrict__ w_ih,
    float* __restrict__ dout, unsigned short* __restrict__ xs_ws)
{
  if (blockIdx.x == 152){
    unsigned short* wa = (unsigned short*)(dout + OFF_WIHR);
    unsigned short* wbb = (unsigned short*)(dout + OFF_WIHR + 16384);
    for (int i = blockIdx.y * 256 + threadIdx.x; i < 2 * NG * WKP + 80; i += NB * 256){
      if (i < NG * WKP){
        int g = i / WKP, kk = i - g * WKP;
        unsigned short v = 0;
        if (kk < GIN){
          int cf = kk / WO, wo = kk - cf * WO;
          v = (unsigned short)bf16r(w_ih[g * GIN + wo * 8 + cf]);
        }
        wa[i] = v;
      } else if (i < 2 * NG * WKP){
        int ii = i - NG * WKP;
        int g = ii / WKP, kk = ii - g * WKP;
        unsigned short v = 0;
        if (kk < GIN) v = (unsigned short)bf16r(w_ih[g * GIN + kk]);
        wbb[ii] = v;
      } else if (i < 2 * NG * WKP + 72){
        dout[OFF_DCNW + (i - 2 * NG * WKP)] = dcn_w[i - 2 * NG * WKP];
      } else {
        dout[OFF_DCNB + (i - 2 * NG * WKP - 72)] = dcn_b[i - 2 * NG * WKP - 72];
      }
    }
    return;
  }
  float* out_dcn = dout + OFF_DCN;

  __shared__ f32x2 owp[81];
  __shared__ f32x2 obp[9];
  __shared__ f32x2 dwp[4][9];
  __shared__ float db[8];
  __shared__ float xl[XLR][41];
  int tid = threadIdx.x;
  if (tid < 81) owp[tid] = (f32x2){offset_w[tid], offset_w[81 + tid]};
  if (tid < 9)  obp[tid] = (f32x2){offset_b[tid], offset_b[9 + tid]};
  if (tid < 36){
    int q = tid / 9, tap = tid - q * 9;
    dwp[q][tap] = (f32x2){dcn_w[(2 * q) * 9 + tap], dcn_w[(2 * q + 1) * 9 + tap]};
  }
  if (tid < 8)  db[tid] = dcn_b[tid];

  int b = blockIdx.y;
  const float* xb = x + (size_t)b * NT * NF;
  int h_base = 2 * ((blockIdx.x * 256) / WO);
  for (int i = tid; i < XLR * NF; i += 256){
    int r = i / NF, cc = i - r * NF;
    int gr = h_base - 3 + r;
    gr = min(max(gr, 0), NT - 1);
    xl[r][cc] = xb[(size_t)gr * NF + cc];
  }
  if (tid < XLR) xl[tid][40] = 0.0f;
  __syncthreads();

  int idx = blockIdx.x * 256 + tid;
  if (idx >= 1023 * WO) return;
  int ho2 = idx / WO, wo = idx - ho2 * WO;
  int ho = ho2 * 2;
  int hrel = ho - h_base + 3;

  float patch[12];
  #pragma unroll
  for (int p = 0; p < 4; p++)
    #pragma unroll
    for (int q = 0; q < 3; q++)
      patch[p * 3 + q] = xl[hrel + p][wo + q];

  f32x2 acc0[4], acc1[4];
  #pragma unroll
  for (int q = 0; q < 4; q++){
    acc0[q] = (f32x2){db[2 * q], db[2 * q + 1]};
    acc1[q] = acc0[q];
  }

  #pragma unroll
  for (int tap = 0; tap < 9; tap++){
    f32x2 off0 = obp[tap], off1 = off0;
    #pragma unroll
    for (int t2 = 0; t2 < 9; t2++){
      f32x2 wp = owp[tap * 9 + t2];
      off0 += wp * (f32x2){patch[t2], patch[t2]};
      off1 += wp * (f32x2){patch[3 + t2], patch[3 + t2]};
    }
    int tr = tap / 3, tc = tap % 3;
    #pragma unroll
    for (int pt = 0; pt < 2; pt++){
      f32x2 off = pt ? off1 : off0;
      float ph = off.x + (float)(ho + pt + tr);
      float pw = off.y + (float)(wo + tc);
      ph = fminf(fmaxf(ph, 0.0f), (float)(NT - 1));
      pw = fminf(fmaxf(pw, 0.0f), (float)(NF - 1));
      int h0 = (int)ph;
      int w0 = (int)pw;
      float lh = ph - (float)h0;
      float lw = pw - (float)w0;
      int hi0 = h0 - h_base + 3;
      const float* rr = &xl[hi0][w0];
      float v00 = rr[0], v01 = rr[1];
      float v10 = rr[41], v11 = rr[42];
      float top = fmaf(lw, v01 - v00, v00);
      float bot = fmaf(lw, v11 - v10, v10);
      float s   = fmaf(lh, bot - top, top);
      f32x2 sp = {s, s};
      f32x2* ac = pt ? acc1 : acc0;
      #pragma unroll
      for (int q = 0; q < 4; q++) ac[q] += dwp[q][tap] * sp;
    }
  }
  size_t base = (size_t)(b * 8) * HW + (size_t)ho * WO + wo;
  #pragma unroll
  for (int q = 0; q < 4; q++){
    out_dcn[base + (size_t)(2 * q) * HW]          = acc0[q].x;
    out_dcn[base + (size_t)(2 * q + 1) * HW]      = acc0[q].y;
    out_dcn[base + (size_t)(2 * q) * HW + WO]     = acc1[q].x;
    out_dcn[base + (size_t)(2 * q + 1) * HW + WO] = acc1[q].y;
  }
  if (XSW){
    size_t xb0 = ((size_t)b * HO + ho) * GIN + wo * 8;
    unsigned short v8[8];
    #pragma unroll
    for (int q = 0; q < 4; q++){
      v8[2 * q]     = (unsigned short)bf16r(acc0[q].x);
      v8[2 * q + 1] = (unsigned short)bf16r(acc0[q].y);
    }
    *(uint4*)&xs_ws[xb0] = *(const uint4*)v8;
    #pragma unroll
    for (int q = 0; q < 4; q++){
      v8[2 * q]     = (unsigned short)bf16r(acc1[q].x);
      v8[2 * q + 1] = (unsigned short)bf16r(acc1[q].y);
    }
    *(uint4*)&xs_ws[xb0 + GIN] = *(const uint4*)v8;
  }
}

// ---------------- K2 (templated on XSWS): gi = (xs @ w^T + bias) * scale,
// bf16 MFMA, K2_M=64, B direct from global bf16 w. r31: gi stored as BF16
// ushorts into the OFF_GI alias region — halves k2's write and k3's read
// traffic (gi already carries bf16-input precision from the MFMA).
#define K2_M 64
template<int XSWS>
__global__ __launch_bounds__(256) void k2_gi_t(
    const float* __restrict__ dro,
    const float* __restrict__ b_ih, const float* __restrict__ b_hh,
    const unsigned short* __restrict__ xs_ws, unsigned short* __restrict__ gi16)
{
  __shared__ unsigned short xsl[K2_M][WKP];   // 41,984 B
  int tid = threadIdx.x;
  int tile = blockIdx.x;   // 0..31
  int b = blockIdx.y;
  int t0 = tile * K2_M;
  const unsigned short* wb = XSWS
      ? (const unsigned short*)(dro + OFF_WIHR + 16384)
      : (const unsigned short*)(dro + OFF_WIHR);

  if (XSWS){
    for (int i = tid; i < K2_M * 38; i += 256){
      int tt = i / 38, q = i - tt * 38;
      int t = t0 + tt;
      uint4 v = {0, 0, 0, 0};
      if (t < HO)
        v = *(const uint4*)&xs_ws[((size_t)b * HO + t) * GIN + q * 8];
      *(uint4*)&xsl[tt][q * 8] = v;
    }
  } else {
    const float* dcn = dro + OFF_DCN;
    for (int i = tid; i < K2_M * 152; i += 256){
      int tt = i / 152, p = i - tt * 152;
      int t = t0 + tt;
      int kp = 2 * p; int cf = kp / WO; int wo = kp - cf * WO;
      unsigned v = 0;
      if (t < HO){
        float2 xv = *(const float2*)&dcn[((size_t)(b * 8 + cf) * HO + t) * WO + wo];
        v = bf16r(xv.x) | (bf16r(xv.y) << 16);
      }
      *(unsigned*)&xsl[tt][kp] = v;
    }
  }
  // zero-pad kp 304..327
  for (int i = tid; i < K2_M * 12; i += 256){
    int tt = i / 12, p = i - tt * 12;
    *(unsigned*)&xsl[tt][GIN + 2 * p] = 0;
  }
  __syncthreads();

  int wv = tid >> 6, l = tid & 63;
  int r16 = l & 15, koct = l >> 4;
  f32x4 acc[6];
  #pragma unroll
  for (int n = 0; n < 6; n++) acc[n] = (f32x4){0.0f, 0.0f, 0.0f, 0.0f};

  #pragma unroll
  for (int ks = 0; ks < 10; ks++){
    int kb = ks * 32 + koct * 8;
    bf16x8 af = *(const bf16x8*)&xsl[wv * 16 + r16][kb];
    #pragma unroll
    for (int n = 0; n < 6; n++){
      bf16x8 bfr = *(const bf16x8*)&wb[(size_t)(n * 16 + r16) * WKP + kb];
      acc[n] = __builtin_amdgcn_mfma_f32_16x16x32_bf16(af, bfr, acc[n], 0, 0, 0);
    }
  }
  #pragma unroll
  for (int n = 0; n < 6; n++){
    int g = n * 16 + r16;
    float sc = (g < 64) ? CG_SCALE : CN_SCALE;
    float bb = b_ih[g] + ((g < 64) ? b_hh[g] : 0.0f);
    #pragma unroll
    for (int reg = 0; reg < 4; reg++){
      int t = t0 + wv * 16 + koct * 4 + reg;
      if (t < HO)
        gi16[((size_t)b * HO + t) * NG + g] =
            (unsigned short)bf16r((acc[n][reg] + bb) * sc);
    }
  }
}

// ---------------- K3: chunked sequential GRU (32 chunks x 64 + 64 burn-in).
// r31: gi read as bf16 (ushort load + <<16 bitcast) — half the read traffic.
#define CHUNKS 32
#define CLEN 64
#define BURN 64
__global__ __launch_bounds__(64) __attribute__((amdgpu_waves_per_eu(1, 2)))
void k3_gru(
    const unsigned short* __restrict__ gi16, const float* __restrict__ w_hh,
    const float* __restrict__ b_hh, float* __restrict__ out_gru)
{
  int b = blockIdx.x;
  int c = blockIdx.y;
  int lane = threadIdx.x;
  int j = lane & 31;
  f32x2 wgp[16], wnp[16];
  #pragma unroll
  for (int m = 0; m < 16; m++){
    wgp[m].x = w_hh[lane * GH + 2 * m]     * CG_SCALE;
    wgp[m].y = w_hh[lane * GH + 2 * m + 1] * CG_SCALE;
    wnp[m].x = w_hh[(64 + j) * GH + 2 * m]     * CN_SCALE;
    wnp[m].y = w_hh[(64 + j) * GH + 2 * m + 1] * CN_SCALE;
  }
  float bn = b_hh[64 + j] * CN_SCALE;
  #pragma unroll
  for (int m = 0; m < 16; m++){
    asm volatile("" : "+v"(wgp[m]), "+v"(wnp[m]));
  }
  asm volatile("" : "+v"(bn));

  __shared__ __align__(16) float hl[64];

  int sstart = c * CLEN;
  int t0 = (c == 0) ? 0 : (sstart - BURN);
  int tend = min(sstart + CLEN, HO);
  int nsteps = tend - t0;
  int nblk = (nsteps + 7) >> 3;

  const unsigned short* gip = gi16 + ((size_t)b * HO + t0) * NG;
  float* og = out_gru + (size_t)b * GH + j;

  float Ag[8], An[8], Bg[8], Bn[8];
  float hj = 0.0f;

  #define LOADBLK(G_, N_, BLK_)                                              \
  {                                                                          \
    const unsigned short* p_ = gip + (size_t)(BLK_) * (8 * NG);              \
    _Pragma("unroll")                                                        \
    for (int s = 0; s < 8; s++){                                             \
      G_[s] = bf2f(p_[s * NG + lane]);                                       \
      N_[s] = bf2f(p_[s * NG + 64 + j]);                                     \
    }                                                                        \
  }

  #define QUAD(Q_, MA_)                                                      \
  {                                                                          \
    f32x2 pA_ = {Q_.x, Q_.y};                                                \
    f32x2 pB_ = {Q_.z, Q_.w};                                                \
    asm("v_pk_fma_f32 %0, %1, %2, %0" : "+v"(ag0) : "v"(wgp[MA_]),     "v"(pA_)); \
    asm("v_pk_fma_f32 %0, %1, %2, %0" : "+v"(an0) : "v"(wnp[MA_]),     "v"(pA_)); \
    asm("v_pk_fma_f32 %0, %1, %2, %0" : "+v"(ag1) : "v"(wgp[MA_ + 1]), "v"(pB_)); \
    asm("v_pk_fma_f32 %0, %1, %2, %0" : "+v"(an1) : "v"(wnp[MA_ + 1]), "v"(pB_)); \
  }

  #define GRU_STEP(GG_, GN_, HS_)                                            \
  {                                                                          \
    hl[lane] = hj;                                                           \
    asm volatile("" ::: "memory");                                           \
    f32x4 q0 = *(const f32x4*)&hl[0];                                        \
    f32x4 q1 = *(const f32x4*)&hl[4];                                        \
    f32x4 q2 = *(const f32x4*)&hl[8];                                        \
    f32x4 q3 = *(const f32x4*)&hl[12];                                       \
    f32x4 q4 = *(const f32x4*)&hl[16];                                       \
    f32x4 q5 = *(const f32x4*)&hl[20];                                       \
    f32x4 q6 = *(const f32x4*)&hl[24];                                       \
    f32x4 q7 = *(const f32x4*)&hl[28];                                       \
    f32x2 ag0 = {0.0f, 0.0f}, ag1 = {0.0f, 0.0f};                            \
    f32x2 an0 = {0.0f, 0.0f}, an1 = {0.0f, 0.0f};                            \
    QUAD(q0, 0)  QUAD(q1, 2)  QUAD(q2, 4)  QUAD(q3, 6)                       \
    QUAD(q4, 8)  QUAD(q5, 10) QUAD(q6, 12) QUAD(q7, 14)                      \
    float sg = (ag0.x + ag0.y) + (ag1.x + ag1.y);                            \
    float sn = (an0.x + an0.y) + (an1.x + an1.y) + bn;                       \
    float g  = rcp_f(1.0f + __builtin_amdgcn_exp2f(GG_ + sg));               \
    float zc = __shfl_xor(g, 32, 64);                                        \
    float nv = fmaf(-2.0f,                                                   \
        rcp_f(__builtin_amdgcn_exp2f(fmaf(g, sn, GN_)) + 1.0f), 1.0f);       \
    hj = fmaf(zc, hj - nv, nv);                                              \
    HS_ = hj;                                                                \
  }

  #define COMPUTE8(G_, N_, BLKI_)                                            \
  {                                                                          \
    float hsv[8];                                                            \
    _Pragma("unroll")                                                        \
    for (int s = 0; s < 8; s++){ GRU_STEP(G_[s], N_[s], hsv[s]); }           \
    int tb_ = t0 + (BLKI_) * 8;                                              \
    if (lane < 32){                                                          \
      _Pragma("unroll")                                                      \
      for (int s = 0; s < 8; s++){                                           \
        int t_ = tb_ + s;                                                    \
        if (t_ >= sstart && t_ < tend)                                       \
          og[(size_t)t_ * (NB * GH)] = hsv[s];                               \
      }                                                                      \
    }                                                                        \
  }

  LOADBLK(Ag, An, 0);
  LOADBLK(Bg, Bn, 1);
  int npair = nblk >> 1;
  for (int p = 0; p < npair; p++){
    int i0 = 2 * p;
    COMPUTE8(Ag, An, i0);
    if (i0 + 2 < nblk) LOADBLK(Ag, An, i0 + 2);
    COMPUTE8(Bg, Bn, i0 + 1);
    if (i0 + 3 < nblk) LOADBLK(Bg, Bn, i0 + 3);
  }
  #undef LOADBLK
  #undef QUAD
  #undef GRU_STEP
  #undef COMPUTE8
}

// ---------------- K4a (templated): a = tanh(enc@w1.T+b1); out_l2 = a@w2.T+b2.
// WSMODE=1: fused k4b1 — per-(tile,b,j) online softmax (m,s) partials -> ws.
template<int WSMODE>
__global__ __launch_bounds__(256) void k4a_att_t(
    const float* __restrict__ out_gru,
    const float* __restrict__ w1, const float* __restrict__ b1,
    const float* __restrict__ w2, const float* __restrict__ b2,
    float* __restrict__ out_l2, float* __restrict__ ws)
{
  __shared__ float w1p[32][33], w2p[32][33], encl[64][32], al[64][33];
  __shared__ float b1l[32], b2l[32];
  __shared__ float mm[8][32], ss[8][32];
  int tid = threadIdx.x;
  int tile = blockIdx.x;   // 0..31
  int b = blockIdx.y;
  if (tid < 32){ b1l[tid] = b1[tid]; b2l[tid] = b2[tid]; }
  for (int i = tid; i < 1024; i += 256){
    int jj = i >> 5, kk = i & 31;
    w1p[jj][kk] = w1[i];
    w2p[jj][kk] = w2[i];
  }
  int t0 = tile * 64;
  for (int i = tid; i < 64 * 32; i += 256){
    int tt = i >> 5, kk = i & 31;
    int t = t0 + tt;
    encl[tt][kk] = (t < HO) ? out_gru[((size_t)t * NB + b) * GH + kk] : 0.0f;
  }
  __syncthreads();
  int j = tid & 31, tq = tid >> 5;  // tq 0..7
  #pragma unroll
  for (int pass = 0; pass < 8; pass++){
    int tt = pass * 8 + tq;
    float a = b1l[j];
    #pragma unroll
    for (int k = 0; k < 32; k++) a += encl[tt][k] * w1p[j][k];
    al[tt][j] = tanh_f(a);
  }
  __syncthreads();
  float m = -INFINITY, s = 0.0f;
  #pragma unroll
  for (int pass = 0; pass < 8; pass++){
    int tt = pass * 8 + tq;
    float v = b2l[j];
    #pragma unroll
    for (int k = 0; k < 32; k++) v += al[tt][k] * w2p[j][k];
    int t = t0 + tt;
    if (t < HO){
      out_l2[((size_t)b * HO + t) * GH + j] = v;
      if (WSMODE){
        float mn = fmaxf(m, v);
        s = s * __expf(m - mn) + __expf(v - mn);
        m = mn;
      }
    }
  }
  if (WSMODE){
    mm[tq][j] = m; ss[tq][j] = s;
    __syncthreads();
    if (tid < 32){
      float M = -INFINITY;
      #pragma unroll
      for (int i = 0; i < 8; i++) M = fmaxf(M, mm[i][tid]);
      float S = 0.0f;
      #pragma unroll
      for (int i = 0; i < 8; i++) S += ss[i][tid] * __expf(mm[i][tid] - M);
      ws[((size_t)(b * 32 + tile) * 32 + tid) * 2]     = M;
      ws[((size_t)(b * 32 + tile) * 32 + tid) * 2 + 1] = S;
    }
  }
}

// ---------------- K4b split kernels
#define K4Q 512
__global__ __launch_bounds__(256) void k4b1_ms(
    const float* __restrict__ out_l2, float* __restrict__ ws)
{
  __shared__ float ml[8][32], sl[8][32];
  int q = blockIdx.x, b = blockIdx.y;
  int tid = threadIdx.x;
  int j = tid & 31, tg = tid >> 5;
  const float* l2b = out_l2 + (size_t)b * HO * GH;
  int t1 = min((q + 1) * K4Q, HO);
  float m = -INFINITY, s = 0.0f;
  for (int t = q * K4Q + tg; t < t1; t += 8){
    float v = l2b[t * GH + j];
    float mn = fmaxf(m, v);
    s = s * __expf(m - mn) + __expf(v - mn);
    m = mn;
  }
  ml[tg][j] = m; sl[tg][j] = s;
  __syncthreads();
  if (tid < 32){
    float M = -INFINITY;
    #pragma unroll
    for (int i = 0; i < 8; i++) M = fmaxf(M, ml[i][tid]);
    float S = 0.0f;
    #pragma unroll
    for (int i = 0; i < 8; i++) S += sl[i][tid] * __expf(ml[i][tid] - M);
    ws[((size_t)(b * 4 + q) * 32 + tid) * 2]     = M;
    ws[((size_t)(b * 4 + q) * 32 + tid) * 2 + 1] = S;
  }
}

template<int NPART, int MUOFF>
__global__ __launch_bounds__(256) void k4b2_norm_t(
    const float* __restrict__ out_l2, const float* __restrict__ out_gru,
    float* __restrict__ ws, float* __restrict__ dout)
{
  __shared__ float pl[8][32];
  int q = blockIdx.x, b = blockIdx.y;
  int tid = threadIdx.x;
  int j = tid & 31, tg = tid >> 5;
  float M = -INFINITY;
  #pragma unroll 4
  for (int i = 0; i < NPART; i++)
    M = fmaxf(M, ws[((size_t)(b * NPART + i) * 32 + j) * 2]);
  float S = 0.0f;
  #pragma unroll 4
  for (int i = 0; i < NPART; i++){
    float mq = ws[((size_t)(b * NPART + i) * 32 + j) * 2];
    float sq = ws[((size_t)(b * NPART + i) * 32 + j) * 2 + 1];
    S += sq * __expf(mq - M);
  }
  float rS = 1.0f / S;
  const float* l2b = out_l2 + (size_t)b * HO * GH;
  float* sm_o  = dout + OFF_SM  + (size_t)b * HO * GH;
  float* mul_o = dout + OFF_MUL + (size_t)b * HO * GH;
  int t1 = min((q + 1) * K4Q, HO);
  float ps = 0.0f;
  for (int t = q * K4Q + tg; t < t1; t += 8){
    float v = l2b[t * GH + j];
    float e = __expf(v - M) * rS;
    float enc = out_gru[((size_t)t * NB + b) * GH + j];
    sm_o[t * GH + j] = e;
    float mu = e * enc;
    mul_o[t * GH + j] = mu;
    ps += mu;
  }
  pl[tg][j] = ps;
  __syncthreads();
  if (tid < 32){
    float P = 0.0f;
    #pragma unroll
    for (int i = 0; i < 8; i++) P += pl[i][tid];
    ws[MUOFF + (size_t)(b * 4 + q) * 32 + tid] = P;
  }
}

template<int MUOFF>
__global__ __launch_bounds__(32) void k4b3_fin_t(
    const float* __restrict__ ws, const float* __restrict__ w3,
    const float* __restrict__ b3, float* __restrict__ dout)
{
  __shared__ float osum[32];
  int b = blockIdx.x;
  int j = threadIdx.x;
  float S2 = 0.0f;
  #pragma unroll
  for (int i = 0; i < 4; i++) S2 += ws[MUOFF + (size_t)(b * 4 + i) * 32 + j];
  dout[OFF_SUM + b * GH + j] = S2;
  osum[j] = S2;
  __syncthreads();
  if (j < 2){
    float L = b3[j];
    #pragma unroll
    for (int k = 0; k < 32; k++) L += w3[j * GH + k] * osum[k];
    dout[OFF_LOGITS + b * 2 + j] = L;
  }
}

// ---------------- K4b fallback (single kernel, used if ws too small)
__global__ __launch_bounds__(1024) void k4b_soft(
    const float* __restrict__ out_l2, const float* __restrict__ out_gru,
    const float* __restrict__ w3, const float* __restrict__ b3,
    float* __restrict__ dout)
{
  __shared__ float ml[32][32], sl[32][32];
  __shared__ float Mf[32], rSf[32];
  __shared__ float pl[32][32];
  __shared__ float osum[32];
  int tid = threadIdx.x;
  int b = blockIdx.x;
  int j = tid & 31, tg = tid >> 5;
  const float* l2b = out_l2 + (size_t)b * HO * GH;
  float m = -INFINITY, s = 0.0f;
  for (int t = tg; t < HO; t += 32){
    float v = l2b[t * GH + j];
    float mn = fmaxf(m, v);
    s = s * __expf(m - mn) + __expf(v - mn);
    m = mn;
  }
  ml[tg][j] = m; sl[tg][j] = s;
  __syncthreads();
  if (tid < 32){
    float M = -INFINITY;
    #pragma unroll
    for (int i = 0; i < 32; i++) M = fmaxf(M, ml[i][tid]);
    float S = 0.0f;
    #pragma unroll
    for (int i = 0; i < 32; i++) S += sl[i][tid] * __expf(ml[i][tid] - M);
    Mf[tid] = M; rSf[tid] = 1.0f / S;
  }
  __syncthreads();
  float M = Mf[j], rS = rSf[j];
  float ps = 0.0f;
  float* sm_o  = dout + OFF_SM  + (size_t)b * HO * GH;
  float* mul_o = dout + OFF_MUL + (size_t)b * HO * GH;
  for (int t = tg; t < HO; t += 32){
    float v = l2b[t * GH + j];
    float e = __expf(v - M) * rS;
    float enc = out_gru[((size_t)t * NB + b) * GH + j];
    sm_o[t * GH + j] = e;
    float mu = e * enc;
    mul_o[t * GH + j] = mu;
    ps += mu;
  }
  pl[tg][j] = ps;
  __syncthreads();
  if (tid < 32){
    float S2 = 0.0f;
    #pragma unroll
    for (int i = 0; i < 32; i++) S2 += pl[i][tid];
    dout[OFF_SUM + b * GH + tid] = S2;
    osum[tid] = S2;
  }
  __syncthreads();
  if (tid < 2){
    float L = b3[tid];
    #pragma unroll
    for (int k = 0; k < 32; k++) L += w3[tid * GH + k] * osum[k];
    dout[OFF_LOGITS + b * 2 + tid] = L;
  }
}

extern "C" void kernel_launch(void* const* d_in, const int* in_sizes, int n_in,
                              void* d_out, int out_size, void* d_ws, size_t ws_size,
                              hipStream_t stream)
{
  const float* x        = (const float*)d_in[0];
  const float* offset_w = (const float*)d_in[1];
  const float* offset_b = (const float*)d_in[2];
  const float* dcn_w    = (const float*)d_in[3];
  const float* dcn_b    = (const float*)d_in[4];
  const float* w_ih     = (const float*)d_in[5];
  const float* w_hh     = (const float*)d_in[6];
  const float* b_ih     = (const float*)d_in[7];
  const float* b_hh     = (const float*)d_in[8];
  const float* w1       = (const float*)d_in[9];
  const float* b1       = (const float*)d_in[10];
  const float* w2       = (const float*)d_in[11];
  const float* b2       = (const float*)d_in[12];
  const float* w3       = (const float*)d_in[13];
  const float* b3       = (const float*)d_in[14];
  float* dout = (float*)d_out;
  float* ws   = (float*)d_ws;
  (void)in_sizes; (void)n_in; (void)out_size;

  // bf16 gi lives inside the OFF_GI alias region of d_out
  unsigned short* gi16 = (unsigned short*)(dout + OFF_GI);

  bool big = ws_size >= (size_t)(XSF + 131072 + 8192) * sizeof(float);
  unsigned short* xsp = (unsigned short*)ws;
  float* wsp = big ? (ws + XSF) : ws;

  if (big){
    k1_deform_t<1><<<dim3(153, NB), 256, 0, stream>>>(x, offset_w, offset_b,
                                                      dcn_w, dcn_b, w_ih, dout, xsp);
    k2_gi_t<1><<<dim3(32, NB), 256, 0, stream>>>(dout, b_ih, b_hh, xsp, gi16);
  } else {
    k1_deform_t<0><<<dim3(153, NB), 256, 0, stream>>>(x, offset_w, offset_b,
                                                      dcn_w, dcn_b, w_ih, dout, nullptr);
    k2_gi_t<0><<<dim3(32, NB), 256, 0, stream>>>(dout, b_ih, b_hh, nullptr, gi16);
  }
  k3_gru<<<dim3(NB, CHUNKS), 64, 0, stream>>>(gi16, w_hh, b_hh, dout + OFF_GRU);

  if (big || ws_size >= (131072 + 8192) * sizeof(float)){
    k4a_att_t<1><<<dim3(32, NB), 256, 0, stream>>>(dout + OFF_GRU, w1, b1, w2, b2,
                                                   dout + OFF_L2, wsp);
    k4b2_norm_t<32, 131072><<<dim3(4, NB), 256, 0, stream>>>(dout + OFF_L2,
                                                             dout + OFF_GRU, wsp, dout);
    k4b3_fin_t<131072><<<NB, 32, 0, stream>>>(wsp, w3, b3, dout);
  } else if (ws_size >= (16384 + 8192) * sizeof(float)){
    k4a_att_t<0><<<dim3(32, NB), 256, 0, stream>>>(dout + OFF_GRU, w1, b1, w2, b2,
                                                   dout + OFF_L2, wsp);
    k4b1_ms<<<dim3(4, NB), 256, 0, stream>>>(dout + OFF_L2, wsp);
    k4b2_norm_t<4, 16384><<<dim3(4, NB), 256, 0, stream>>>(dout + OFF_L2,
                                                           dout + OFF_GRU, wsp, dout);
    k4b3_fin_t<16384><<<NB, 32, 0, stream>>>(wsp, w3, b3, dout);
  } else {
    k4a_att_t<0><<<dim3(32, NB), 256, 0, stream>>>(dout + OFF_GRU, w1, b1, w2, b2,
                                                   dout + OFF_L2, wsp);
    k4b_soft<<<NB, 1024, 0, stream>>>(dout + OFF_L2, dout + OFF_GRU, w3, b3, dout);
  }
}

// Round 32
// 245.561 us; speedup vs baseline: 1.0227x; 1.0227x over previous
//
#include <hip/hip_runtime.h>
#include <math.h>

#define NB 64
#define NT 2048
#define NF 40
#define HO 2046
#define WO 38
#define HW 77748          // HO*WO
#define GIN 304
#define NG 96
#define GH 32

// d_out float offsets (flat concat in return order)
#define OFF_LOGITS 0
#define OFF_SUM    128
#define OFF_MUL    2176
#define OFF_SM     4192384
#define OFF_L2     8382592
#define OFF_GRU    12572800
#define OFF_DCN    16763008
#define OFF_DCNW   56569984
#define OFF_DCNB   56570056
// scratch aliases inside d_out:
#define OFF_GI     OFF_MUL    // 12,570,624 floats == MUL+SM+L2 regions exactly
#define OFF_WIHR   OFF_GRU    // bf16 w layouts (2 x 15,744 floats), consumed by K2, overwritten by K3

#define CG_SCALE (-1.44269504088896340736f)
#define CN_SCALE ( 2.88539008177792681472f)

// ws layout (floats) for the big-ws path: [0, XSF) bf16 xs tensor
// (64*2046*304 ushorts = 39,806,976), then softmax partials.
#define XSF 19903488

typedef float f32x2 __attribute__((ext_vector_type(2)));
typedef float f32x4 __attribute__((ext_vector_type(4)));
typedef short bf16x8 __attribute__((ext_vector_type(8)));
typedef unsigned long long u64;

__device__ __forceinline__ float rcp_f(float x){
  return __builtin_amdgcn_rcpf(x);
}
__device__ __forceinline__ float tanh_f(float x){
  return 1.0f - 2.0f * rcp_f(__expf(2.0f * x) + 1.0f);
}
__device__ __forceinline__ unsigned bf16r(float x){   // RNE f32->bf16
  unsigned u = __float_as_uint(x);
  return (u + 0x7FFFu + ((u >> 16) & 1u)) >> 16;
}

#define WKP 328

// ---------------- K1 (templated on XSW): fused offset-conv + deformable
// bilinear + DCN einsum. LDS x-window (r25), 2 pts/thread + packed f32x2
// (r22), (256,6) (r23), r27 sample diet. Merged k0 slice writes BOTH w
// layouts: wb_a (kp=cf*38+wo, for the dcn-reading k2 fallback) and wb_b
// (identity k order kp'=wo*8+cf, for the ws-xs k2). XSW=1 (r30): also emit
// bf16 xs rows [b][t][wo*8+cf] into ws — one 16B coalesced store per point —
// halving k2's read traffic and removing its conversion work.
#define XLR 26
template<int XSW>
__global__ __launch_bounds__(256, 6) void k1_deform_t(
    const float* __restrict__ x, const float* __restrict__ offset_w,
    const float* __restrict__ offset_b, const float* __restrict__ dcn_w,
    const float* __restrict__ dcn_b, const float* __restrict__ w_ih,
    float* __restrict__ dout, unsigned short* __restrict__ xs_ws)
{
  if (blockIdx.x == 152){
    unsigned short* wa = (unsigned short*)(dout + OFF_WIHR);
    unsigned short* wbb = (unsigned short*)(dout + OFF_WIHR + 16384);
    for (int i = blockIdx.y * 256 + threadIdx.x; i < 2 * NG * WKP + 80; i += NB * 256){
      if (i < NG * WKP){
        int g = i / WKP, kk = i - g * WKP;
        unsigned short v = 0;
        if (kk < GIN){
          int cf = kk / WO, wo = kk - cf * WO;
          v = (unsigned short)bf16r(w_ih[g * GIN + wo * 8 + cf]);
        }
        wa[i] = v;
      } else if (i < 2 * NG * WKP){
        int ii = i - NG * WKP;
        int g = ii / WKP, kk = ii - g * WKP;
        unsigned short v = 0;
        if (kk < GIN) v = (unsigned short)bf16r(w_ih[g * GIN + kk]);
        wbb[ii] = v;
      } else if (i < 2 * NG * WKP + 72){
        dout[OFF_DCNW + (i - 2 * NG * WKP)] = dcn_w[i - 2 * NG * WKP];
      } else {
        dout[OFF_DCNB + (i - 2 * NG * WKP - 72)] = dcn_b[i - 2 * NG * WKP - 72];
      }
    }
    return;
  }
  float* out_dcn = dout + OFF_DCN;

  __shared__ f32x2 owp[81];
  __shared__ f32x2 obp[9];
  __shared__ f32x2 dwp[4][9];
  __shared__ float db[8];
  __shared__ float xl[XLR][41];
  int tid = threadIdx.x;
  if (tid < 81) owp[tid] = (f32x2){offset_w[tid], offset_w[81 + tid]};
  if (tid < 9)  obp[tid] = (f32x2){offset_b[tid], offset_b[9 + tid]};
  if (tid < 36){
    int q = tid / 9, tap = tid - q * 9;
    dwp[q][tap] = (f32x2){dcn_w[(2 * q) * 9 + tap], dcn_w[(2 * q + 1) * 9 + tap]};
  }
  if (tid < 8)  db[tid] = dcn_b[tid];

  int b = blockIdx.y;
  const float* xb = x + (size_t)b * NT * NF;
  int h_base = 2 * ((blockIdx.x * 256) / WO);
  for (int i = tid; i < XLR * NF; i += 256){
    int r = i / NF, cc = i - r * NF;
    int gr = h_base - 3 + r;
    gr = min(max(gr, 0), NT - 1);
    xl[r][cc] = xb[(size_t)gr * NF + cc];
  }
  if (tid < XLR) xl[tid][40] = 0.0f;
  __syncthreads();

  int idx = blockIdx.x * 256 + tid;
  if (idx >= 1023 * WO) return;
  int ho2 = idx / WO, wo = idx - ho2 * WO;
  int ho = ho2 * 2;
  int hrel = ho - h_base + 3;

  float patch[12];
  #pragma unroll
  for (int p = 0; p < 4; p++)
    #pragma unroll
    for (int q = 0; q < 3; q++)
      patch[p * 3 + q] = xl[hrel + p][wo + q];

  f32x2 acc0[4], acc1[4];
  #pragma unroll
  for (int q = 0; q < 4; q++){
    acc0[q] = (f32x2){db[2 * q], db[2 * q + 1]};
    acc1[q] = acc0[q];
  }

  #pragma unroll
  for (int tap = 0; tap < 9; tap++){
    f32x2 off0 = obp[tap], off1 = off0;
    #pragma unroll
    for (int t2 = 0; t2 < 9; t2++){
      f32x2 wp = owp[tap * 9 + t2];
      off0 += wp * (f32x2){patch[t2], patch[t2]};
      off1 += wp * (f32x2){patch[3 + t2], patch[3 + t2]};
    }
    int tr = tap / 3, tc = tap % 3;
    #pragma unroll
    for (int pt = 0; pt < 2; pt++){
      f32x2 off = pt ? off1 : off0;
      float ph = off.x + (float)(ho + pt + tr);
      float pw = off.y + (float)(wo + tc);
      ph = fminf(fmaxf(ph, 0.0f), (float)(NT - 1));
      pw = fminf(fmaxf(pw, 0.0f), (float)(NF - 1));
      int h0 = (int)ph;
      int w0 = (int)pw;
      float lh = ph - (float)h0;
      float lw = pw - (float)w0;
      int hi0 = h0 - h_base + 3;
      const float* rr = &xl[hi0][w0];
      float v00 = rr[0], v01 = rr[1];
      float v10 = rr[41], v11 = rr[42];
      float top = fmaf(lw, v01 - v00, v00);
      float bot = fmaf(lw, v11 - v10, v10);
      float s   = fmaf(lh, bot - top, top);
      f32x2 sp = {s, s};
      f32x2* ac = pt ? acc1 : acc0;
      #pragma unroll
      for (int q = 0; q < 4; q++) ac[q] += dwp[q][tap] * sp;
    }
  }
  size_t base = (size_t)(b * 8) * HW + (size_t)ho * WO + wo;
  #pragma unroll
  for (int q = 0; q < 4; q++){
    out_dcn[base + (size_t)(2 * q) * HW]          = acc0[q].x;
    out_dcn[base + (size_t)(2 * q + 1) * HW]      = acc0[q].y;
    out_dcn[base + (size_t)(2 * q) * HW + WO]     = acc1[q].x;
    out_dcn[base + (size_t)(2 * q + 1) * HW + WO] = acc1[q].y;
  }
  if (XSW){
    // bf16 xs rows, identity k order: [b][t][wo*8 + cf], 16B/point, coalesced
    size_t xb0 = ((size_t)b * HO + ho) * GIN + wo * 8;
    unsigned short v8[8];
    #pragma unroll
    for (int q = 0; q < 4; q++){
      v8[2 * q]     = (unsigned short)bf16r(acc0[q].x);
      v8[2 * q + 1] = (unsigned short)bf16r(acc0[q].y);
    }
    *(uint4*)&xs_ws[xb0] = *(const uint4*)v8;
    #pragma unroll
    for (int q = 0; q < 4; q++){
      v8[2 * q]     = (unsigned short)bf16r(acc1[q].x);
      v8[2 * q + 1] = (unsigned short)bf16r(acc1[q].y);
    }
    *(uint4*)&xs_ws[xb0 + GIN] = *(const uint4*)v8;
  }
}

// ---------------- K2 (templated on XSWS): gi = (xs @ w^T + bias) * scale,
// bf16 MFMA, K2_M=64, 4 waves, B-fragments direct from global bf16 w (r29).
// XSWS=1: stage xs rows straight from the bf16 ws tensor (uint4 copies,
// half the traffic, zero conversion) with identity-k w layout (wb_b).
// XSWS=0: r29 path — gather from fp32 dcn + convert, cf*38+wo layout (wb_a).
#define K2_M 64
template<int XSWS>
__global__ __launch_bounds__(256) void k2_gi_t(
    const float* __restrict__ dro,
    const float* __restrict__ b_ih, const float* __restrict__ b_hh,
    const unsigned short* __restrict__ xs_ws, float* __restrict__ gi)
{
  __shared__ unsigned short xsl[K2_M][WKP];   // 41,984 B
  int tid = threadIdx.x;
  int tile = blockIdx.x;   // 0..31
  int b = blockIdx.y;
  int t0 = tile * K2_M;
  const unsigned short* wb = XSWS
      ? (const unsigned short*)(dro + OFF_WIHR + 16384)
      : (const unsigned short*)(dro + OFF_WIHR);

  if (XSWS){
    // copy 64 rows x 38 uint4 from ws
    for (int i = tid; i < K2_M * 38; i += 256){
      int tt = i / 38, q = i - tt * 38;
      int t = t0 + tt;
      uint4 v = {0, 0, 0, 0};
      if (t < HO)
        v = *(const uint4*)&xs_ws[((size_t)b * HO + t) * GIN + q * 8];
      *(uint4*)&xsl[tt][q * 8] = v;
    }
  } else {
    const float* dcn = dro + OFF_DCN;
    for (int i = tid; i < K2_M * 152; i += 256){
      int tt = i / 152, p = i - tt * 152;
      int t = t0 + tt;
      int kp = 2 * p; int cf = kp / WO; int wo = kp - cf * WO;
      unsigned v = 0;
      if (t < HO){
        float2 xv = *(const float2*)&dcn[((size_t)(b * 8 + cf) * HO + t) * WO + wo];
        v = bf16r(xv.x) | (bf16r(xv.y) << 16);
      }
      *(unsigned*)&xsl[tt][kp] = v;
    }
  }
  // zero-pad kp 304..327
  for (int i = tid; i < K2_M * 12; i += 256){
    int tt = i / 12, p = i - tt * 12;
    *(unsigned*)&xsl[tt][GIN + 2 * p] = 0;
  }
  __syncthreads();

  int wv = tid >> 6, l = tid & 63;
  int r16 = l & 15, koct = l >> 4;
  f32x4 acc[6];
  #pragma unroll
  for (int n = 0; n < 6; n++) acc[n] = (f32x4){0.0f, 0.0f, 0.0f, 0.0f};

  #pragma unroll
  for (int ks = 0; ks < 10; ks++){
    int kb = ks * 32 + koct * 8;
    bf16x8 af = *(const bf16x8*)&xsl[wv * 16 + r16][kb];
    #pragma unroll
    for (int n = 0; n < 6; n++){
      bf16x8 bfr = *(const bf16x8*)&wb[(size_t)(n * 16 + r16) * WKP + kb];
      acc[n] = __builtin_amdgcn_mfma_f32_16x16x32_bf16(af, bfr, acc[n], 0, 0, 0);
    }
  }
  #pragma unroll
  for (int n = 0; n < 6; n++){
    int g = n * 16 + r16;
    float sc = (g < 64) ? CG_SCALE : CN_SCALE;
    float bb = b_ih[g] + ((g < 64) ? b_hh[g] : 0.0f);
    #pragma unroll
    for (int reg = 0; reg < 4; reg++){
      int t = t0 + wv * 16 + koct * 4 + reg;
      if (t < HO)
        gi[((size_t)b * HO + t) * NG + g] = (acc[n][reg] + bb) * sc;
    }
  }
}

// ---------------- K3: chunked sequential GRU (32 chunks x 64 + 64 burn-in).
#define CHUNKS 32
#define CLEN 64
#define BURN 64
__global__ __launch_bounds__(64) __attribute__((amdgpu_waves_per_eu(1, 2)))
void k3_gru(
    const float* __restrict__ gi, const float* __restrict__ w_hh,
    const float* __restrict__ b_hh, float* __restrict__ out_gru)
{
  int b = blockIdx.x;
  int c = blockIdx.y;
  int lane = threadIdx.x;
  int j = lane & 31;
  f32x2 wgp[16], wnp[16];
  #pragma unroll
  for (int m = 0; m < 16; m++){
    wgp[m].x = w_hh[lane * GH + 2 * m]     * CG_SCALE;
    wgp[m].y = w_hh[lane * GH + 2 * m + 1] * CG_SCALE;
    wnp[m].x = w_hh[(64 + j) * GH + 2 * m]     * CN_SCALE;
    wnp[m].y = w_hh[(64 + j) * GH + 2 * m + 1] * CN_SCALE;
  }
  float bn = b_hh[64 + j] * CN_SCALE;
  #pragma unroll
  for (int m = 0; m < 16; m++){
    asm volatile("" : "+v"(wgp[m]), "+v"(wnp[m]));
  }
  asm volatile("" : "+v"(bn));

  __shared__ __align__(16) float hl[64];

  int sstart = c * CLEN;
  int t0 = (c == 0) ? 0 : (sstart - BURN);
  int tend = min(sstart + CLEN, HO);
  int nsteps = tend - t0;
  int nblk = (nsteps + 7) >> 3;

  const float* gip = gi + ((size_t)b * HO + t0) * NG;
  float* og = out_gru + (size_t)b * GH + j;

  float Ag[8], An[8], Bg[8], Bn[8];
  float hj = 0.0f;

  #define LOADBLK(G_, N_, BLK_)                                              \
  {                                                                          \
    const float* p_ = gip + (size_t)(BLK_) * (8 * NG);                       \
    _Pragma("unroll")                                                        \
    for (int s = 0; s < 8; s++){                                             \
      G_[s] = p_[s * NG + lane];                                             \
      N_[s] = p_[s * NG + 64 + j];                                           \
    }                                                                        \
  }

  #define QUAD(Q_, MA_)                                                      \
  {                                                                          \
    f32x2 pA_ = {Q_.x, Q_.y};                                                \
    f32x2 pB_ = {Q_.z, Q_.w};                                                \
    asm("v_pk_fma_f32 %0, %1, %2, %0" : "+v"(ag0) : "v"(wgp[MA_]),     "v"(pA_)); \
    asm("v_pk_fma_f32 %0, %1, %2, %0" : "+v"(an0) : "v"(wnp[MA_]),     "v"(pA_)); \
    asm("v_pk_fma_f32 %0, %1, %2, %0" : "+v"(ag1) : "v"(wgp[MA_ + 1]), "v"(pB_)); \
    asm("v_pk_fma_f32 %0, %1, %2, %0" : "+v"(an1) : "v"(wnp[MA_ + 1]), "v"(pB_)); \
  }

  #define GRU_STEP(GG_, GN_, HS_)                                            \
  {                                                                          \
    hl[lane] = hj;                                                           \
    asm volatile("" ::: "memory");                                           \
    f32x4 q0 = *(const f32x4*)&hl[0];                                        \
    f32x4 q1 = *(const f32x4*)&hl[4];                                        \
    f32x4 q2 = *(const f32x4*)&hl[8];                                        \
    f32x4 q3 = *(const f32x4*)&hl[12];                                       \
    f32x4 q4 = *(const f32x4*)&hl[16];                                       \
    f32x4 q5 = *(const f32x4*)&hl[20];                                       \
    f32x4 q6 = *(const f32x4*)&hl[24];                                       \
    f32x4 q7 = *(const f32x4*)&hl[28];                                       \
    f32x2 ag0 = {0.0f, 0.0f}, ag1 = {0.0f, 0.0f};                            \
    f32x2 an0 = {0.0f, 0.0f}, an1 = {0.0f, 0.0f};                            \
    QUAD(q0, 0)  QUAD(q1, 2)  QUAD(q2, 4)  QUAD(q3, 6)                       \
    QUAD(q4, 8)  QUAD(q5, 10) QUAD(q6, 12) QUAD(q7, 14)                      \
    float sg = (ag0.x + ag0.y) + (ag1.x + ag1.y);                            \
    float sn = (an0.x + an0.y) + (an1.x + an1.y) + bn;                       \
    float g  = rcp_f(1.0f + __builtin_amdgcn_exp2f(GG_ + sg));               \
    float zc = __shfl_xor(g, 32, 64);                                        \
    float nv = fmaf(-2.0f,                                                   \
        rcp_f(__builtin_amdgcn_exp2f(fmaf(g, sn, GN_)) + 1.0f), 1.0f);       \
    hj = fmaf(zc, hj - nv, nv);                                              \
    HS_ = hj;                                                                \
  }

  #define COMPUTE8(G_, N_, BLKI_)                                            \
  {                                                                          \
    float hsv[8];                                                            \
    _Pragma("unroll")                                                        \
    for (int s = 0; s < 8; s++){ GRU_STEP(G_[s], N_[s], hsv[s]); }           \
    int tb_ = t0 + (BLKI_) * 8;                                              \
    if (lane < 32){                                                          \
      _Pragma("unroll")                                                      \
      for (int s = 0; s < 8; s++){                                           \
        int t_ = tb_ + s;                                                    \
        if (t_ >= sstart && t_ < tend)                                       \
          og[(size_t)t_ * (NB * GH)] = hsv[s];                               \
      }                                                                      \
    }                                                                        \
  }

  LOADBLK(Ag, An, 0);
  LOADBLK(Bg, Bn, 1);
  int npair = nblk >> 1;
  for (int p = 0; p < npair; p++){
    int i0 = 2 * p;
    COMPUTE8(Ag, An, i0);
    if (i0 + 2 < nblk) LOADBLK(Ag, An, i0 + 2);
    COMPUTE8(Bg, Bn, i0 + 1);
    if (i0 + 3 < nblk) LOADBLK(Bg, Bn, i0 + 3);
  }
  #undef LOADBLK
  #undef QUAD
  #undef GRU_STEP
  #undef COMPUTE8
}

// ---------------- K4a (templated): a = tanh(enc@w1.T+b1); out_l2 = a@w2.T+b2.
// WSMODE=1: fused k4b1 — per-(tile,b,j) online softmax (m,s) partials -> ws.
template<int WSMODE>
__global__ __launch_bounds__(256) void k4a_att_t(
    const float* __restrict__ out_gru,
    const float* __restrict__ w1, const float* __restrict__ b1,
    const float* __restrict__ w2, const float* __restrict__ b2,
    float* __restrict__ out_l2, float* __restrict__ ws)
{
  __shared__ float w1p[32][33], w2p[32][33], encl[64][32], al[64][33];
  __shared__ float b1l[32], b2l[32];
  __shared__ float mm[8][32], ss[8][32];
  int tid = threadIdx.x;
  int tile = blockIdx.x;   // 0..31
  int b = blockIdx.y;
  if (tid < 32){ b1l[tid] = b1[tid]; b2l[tid] = b2[tid]; }
  for (int i = tid; i < 1024; i += 256){
    int jj = i >> 5, kk = i & 31;
    w1p[jj][kk] = w1[i];
    w2p[jj][kk] = w2[i];
  }
  int t0 = tile * 64;
  for (int i = tid; i < 64 * 32; i += 256){
    int tt = i >> 5, kk = i & 31;
    int t = t0 + tt;
    encl[tt][kk] = (t < HO) ? out_gru[((size_t)t * NB + b) * GH + kk] : 0.0f;
  }
  __syncthreads();
  int j = tid & 31, tq = tid >> 5;  // tq 0..7
  #pragma unroll
  for (int pass = 0; pass < 8; pass++){
    int tt = pass * 8 + tq;
    float a = b1l[j];
    #pragma unroll
    for (int k = 0; k < 32; k++) a += encl[tt][k] * w1p[j][k];
    al[tt][j] = tanh_f(a);
  }
  __syncthreads();
  float m = -INFINITY, s = 0.0f;
  #pragma unroll
  for (int pass = 0; pass < 8; pass++){
    int tt = pass * 8 + tq;
    float v = b2l[j];
    #pragma unroll
    for (int k = 0; k < 32; k++) v += al[tt][k] * w2p[j][k];
    int t = t0 + tt;
    if (t < HO){
      out_l2[((size_t)b * HO + t) * GH + j] = v;
      if (WSMODE){
        float mn = fmaxf(m, v);
        s = s * __expf(m - mn) + __expf(v - mn);
        m = mn;
      }
    }
  }
  if (WSMODE){
    mm[tq][j] = m; ss[tq][j] = s;
    __syncthreads();
    if (tid < 32){
      float M = -INFINITY;
      #pragma unroll
      for (int i = 0; i < 8; i++) M = fmaxf(M, mm[i][tid]);
      float S = 0.0f;
      #pragma unroll
      for (int i = 0; i < 8; i++) S += ss[i][tid] * __expf(mm[i][tid] - M);
      ws[((size_t)(b * 32 + tile) * 32 + tid) * 2]     = M;
      ws[((size_t)(b * 32 + tile) * 32 + tid) * 2 + 1] = S;
    }
  }
}

// ---------------- K4b split kernels
#define K4Q 512
__global__ __launch_bounds__(256) void k4b1_ms(
    const float* __restrict__ out_l2, float* __restrict__ ws)
{
  __shared__ float ml[8][32], sl[8][32];
  int q = blockIdx.x, b = blockIdx.y;
  int tid = threadIdx.x;
  int j = tid & 31, tg = tid >> 5;
  const float* l2b = out_l2 + (size_t)b * HO * GH;
  int t1 = min((q + 1) * K4Q, HO);
  float m = -INFINITY, s = 0.0f;
  for (int t = q * K4Q + tg; t < t1; t += 8){
    float v = l2b[t * GH + j];
    float mn = fmaxf(m, v);
    s = s * __expf(m - mn) + __expf(v - mn);
    m = mn;
  }
  ml[tg][j] = m; sl[tg][j] = s;
  __syncthreads();
  if (tid < 32){
    float M = -INFINITY;
    #pragma unroll
    for (int i = 0; i < 8; i++) M = fmaxf(M, ml[i][tid]);
    float S = 0.0f;
    #pragma unroll
    for (int i = 0; i < 8; i++) S += sl[i][tid] * __expf(ml[i][tid] - M);
    ws[((size_t)(b * 4 + q) * 32 + tid) * 2]     = M;
    ws[((size_t)(b * 4 + q) * 32 + tid) * 2 + 1] = S;
  }
}

template<int NPART, int MUOFF>
__global__ __launch_bounds__(256) void k4b2_norm_t(
    const float* __restrict__ out_l2, const float* __restrict__ out_gru,
    float* __restrict__ ws, float* __restrict__ dout)
{
  __shared__ float pl[8][32];
  int q = blockIdx.x, b = blockIdx.y;
  int tid = threadIdx.x;
  int j = tid & 31, tg = tid >> 5;
  float M = -INFINITY;
  #pragma unroll 4
  for (int i = 0; i < NPART; i++)
    M = fmaxf(M, ws[((size_t)(b * NPART + i) * 32 + j) * 2]);
  float S = 0.0f;
  #pragma unroll 4
  for (int i = 0; i < NPART; i++){
    float mq = ws[((size_t)(b * NPART + i) * 32 + j) * 2];
    float sq = ws[((size_t)(b * NPART + i) * 32 + j) * 2 + 1];
    S += sq * __expf(mq - M);
  }
  float rS = 1.0f / S;
  const float* l2b = out_l2 + (size_t)b * HO * GH;
  float* sm_o  = dout + OFF_SM  + (size_t)b * HO * GH;
  float* mul_o = dout + OFF_MUL + (size_t)b * HO * GH;
  int t1 = min((q + 1) * K4Q, HO);
  float ps = 0.0f;
  for (int t = q * K4Q + tg; t < t1; t += 8){
    float v = l2b[t * GH + j];
    float e = __expf(v - M) * rS;
    float enc = out_gru[((size_t)t * NB + b) * GH + j];
    sm_o[t * GH + j] = e;
    float mu = e * enc;
    mul_o[t * GH + j] = mu;
    ps += mu;
  }
  pl[tg][j] = ps;
  __syncthreads();
  if (tid < 32){
    float P = 0.0f;
    #pragma unroll
    for (int i = 0; i < 8; i++) P += pl[i][tid];
    ws[MUOFF + (size_t)(b * 4 + q) * 32 + tid] = P;
  }
}

template<int MUOFF>
__global__ __launch_bounds__(32) void k4b3_fin_t(
    const float* __restrict__ ws, const float* __restrict__ w3,
    const float* __restrict__ b3, float* __restrict__ dout)
{
  __shared__ float osum[32];
  int b = blockIdx.x;
  int j = threadIdx.x;
  float S2 = 0.0f;
  #pragma unroll
  for (int i = 0; i < 4; i++) S2 += ws[MUOFF + (size_t)(b * 4 + i) * 32 + j];
  dout[OFF_SUM + b * GH + j] = S2;
  osum[j] = S2;
  __syncthreads();
  if (j < 2){
    float L = b3[j];
    #pragma unroll
    for (int k = 0; k < 32; k++) L += w3[j * GH + k] * osum[k];
    dout[OFF_LOGITS + b * 2 + j] = L;
  }
}

// ---------------- K4b fallback (single kernel, used if ws too small)
__global__ __launch_bounds__(1024) void k4b_soft(
    const float* __restrict__ out_l2, const float* __restrict__ out_gru,
    const float* __restrict__ w3, const float* __restrict__ b3,
    float* __restrict__ dout)
{
  __shared__ float ml[32][32], sl[32][32];
  __shared__ float Mf[32], rSf[32];
  __shared__ float pl[32][32];
  __shared__ float osum[32];
  int tid = threadIdx.x;
  int b = blockIdx.x;
  int j = tid & 31, tg = tid >> 5;
  const float* l2b = out_l2 + (size_t)b * HO * GH;
  float m = -INFINITY, s = 0.0f;
  for (int t = tg; t < HO; t += 32){
    float v = l2b[t * GH + j];
    float mn = fmaxf(m, v);
    s = s * __expf(m - mn) + __expf(v - mn);
    m = mn;
  }
  ml[tg][j] = m; sl[tg][j] = s;
  __syncthreads();
  if (tid < 32){
    float M = -INFINITY;
    #pragma unroll
    for (int i = 0; i < 32; i++) M = fmaxf(M, ml[i][tid]);
    float S = 0.0f;
    #pragma unroll
    for (int i = 0; i < 32; i++) S += sl[i][tid] * __expf(ml[i][tid] - M);
    Mf[tid] = M; rSf[tid] = 1.0f / S;
  }
  __syncthreads();
  float M = Mf[j], rS = rSf[j];
  float ps = 0.0f;
  float* sm_o  = dout + OFF_SM  + (size_t)b * HO * GH;
  float* mul_o = dout + OFF_MUL + (size_t)b * HO * GH;
  for (int t = tg; t < HO; t += 32){
    float v = l2b[t * GH + j];
    float e = __expf(v - M) * rS;
    float enc = out_gru[((size_t)t * NB + b) * GH + j];
    sm_o[t * GH + j] = e;
    float mu = e * enc;
    mul_o[t * GH + j] = mu;
    ps += mu;
  }
  pl[tg][j] = ps;
  __syncthreads();
  if (tid < 32){
    float S2 = 0.0f;
    #pragma unroll
    for (int i = 0; i < 32; i++) S2 += pl[i][tid];
    dout[OFF_SUM + b * GH + tid] = S2;
    osum[tid] = S2;
  }
  __syncthreads();
  if (tid < 2){
    float L = b3[tid];
    #pragma unroll
    for (int k = 0; k < 32; k++) L += w3[tid * GH + k] * osum[k];
    dout[OFF_LOGITS + b * 2 + tid] = L;
  }
}

extern "C" void kernel_launch(void* const* d_in, const int* in_sizes, int n_in,
                              void* d_out, int out_size, void* d_ws, size_t ws_size,
                              hipStream_t stream)
{
  const float* x        = (const float*)d_in[0];
  const float* offset_w = (const float*)d_in[1];
  const float* offset_b = (const float*)d_in[2];
  const float* dcn_w    = (const float*)d_in[3];
  const float* dcn_b    = (const float*)d_in[4];
  const float* w_ih     = (const float*)d_in[5];
  const float* w_hh     = (const float*)d_in[6];
  const float* b_ih     = (const float*)d_in[7];
  const float* b_hh     = (const float*)d_in[8];
  const float* w1       = (const float*)d_in[9];
  const float* b1       = (const float*)d_in[10];
  const float* w2       = (const float*)d_in[11];
  const float* b2       = (const float*)d_in[12];
  const float* w3       = (const float*)d_in[13];
  const float* b3       = (const float*)d_in[14];
  float* dout = (float*)d_out;
  float* ws   = (float*)d_ws;
  (void)in_sizes; (void)n_in; (void)out_size;

  // big-ws path: bf16 xs tensor (XSF floats) + fused softmax partials
  bool big = ws_size >= (size_t)(XSF + 131072 + 8192) * sizeof(float);
  unsigned short* xsp = (unsigned short*)ws;
  float* wsp = big ? (ws + XSF) : ws;   // softmax partial region

  if (big){
    k1_deform_t<1><<<dim3(153, NB), 256, 0, stream>>>(x, offset_w, offset_b,
                                                      dcn_w, dcn_b, w_ih, dout, xsp);
    k2_gi_t<1><<<dim3(32, NB), 256, 0, stream>>>(dout, b_ih, b_hh, xsp,
                                                 dout + OFF_GI);
  } else {
    k1_deform_t<0><<<dim3(153, NB), 256, 0, stream>>>(x, offset_w, offset_b,
                                                      dcn_w, dcn_b, w_ih, dout, nullptr);
    k2_gi_t<0><<<dim3(32, NB), 256, 0, stream>>>(dout, b_ih, b_hh, nullptr,
                                                 dout + OFF_GI);
  }
  k3_gru<<<dim3(NB, CHUNKS), 64, 0, stream>>>(dout + OFF_GI, w_hh, b_hh,
                                              dout + OFF_GRU);

  if (big || ws_size >= (131072 + 8192) * sizeof(float)){
    k4a_att_t<1><<<dim3(32, NB), 256, 0, stream>>>(dout + OFF_GRU, w1, b1, w2, b2,
                                                   dout + OFF_L2, wsp);
    k4b2_norm_t<32, 131072><<<dim3(4, NB), 256, 0, stream>>>(dout + OFF_L2,
                                                             dout + OFF_GRU, wsp, dout);
    k4b3_fin_t<131072><<<NB, 32, 0, stream>>>(wsp, w3, b3, dout);
  } else if (ws_size >= (16384 + 8192) * sizeof(float)){
    k4a_att_t<0><<<dim3(32, NB), 256, 0, stream>>>(dout + OFF_GRU, w1, b1, w2, b2,
                                                   dout + OFF_L2, wsp);
    k4b1_ms<<<dim3(4, NB), 256, 0, stream>>>(dout + OFF_L2, wsp);
    k4b2_norm_t<4, 16384><<<dim3(4, NB), 256, 0, stream>>>(dout + OFF_L2,
                                                           dout + OFF_GRU, wsp, dout);
    k4b3_fin_t<16384><<<NB, 32, 0, stream>>>(wsp, w3, b3, dout);
  } else {
    k4a_att_t<0><<<dim3(32, NB), 256, 0, stream>>>(dout + OFF_GRU, w1, b1, w2, b2,
                                                   dout + OFF_L2, wsp);
    k4b_soft<<<NB, 1024, 0, stream>>>(dout + OFF_L2, dout + OFF_GRU, w3, b3, dout);
  }
}